// Round 1
// baseline (220.507 us; speedup 1.0000x reference)
//
#include <hip/hip_runtime.h>

static constexpr int   Bn      = 32;
static constexpr int   Tn      = 2000;
static constexpr int   Hn      = 512;
static constexpr int   Ln      = 256;     // max_label_len
static constexpr float kThresh = 0.95f;
static constexpr int   TCHUNK  = 125;
static constexpr int   NTCH    = Tn / TCHUNK;   // 16

// ---------------------------------------------------------------------------
// Phase 1: per-batch-row sequential integrate-and-fire scan (exact f32 replay
// of the reference recurrence, same operation order -> bit-exact fire bits).
// Produces per-(b,t): w1 (weight into segment seg), w2 (weight into seg+1,
// nonzero only on fire), seg (pending fire index), and per-row fire count.
// ---------------------------------------------------------------------------
__global__ void cif_scan_kernel(const float* __restrict__ alphas,
                                float* __restrict__ w1,
                                float* __restrict__ w2,
                                int* __restrict__ seg,
                                int* __restrict__ fcnt) {
  int b = threadIdx.x;
  if (b >= Bn) return;
  const float* arow = alphas + (size_t)b * Tn;
  float* w1r = w1 + (size_t)b * Tn;
  float* w2r = w2 + (size_t)b * Tn;
  int*   sgr = seg + (size_t)b * Tn;
  float integrate = 0.0f;
  int fc = 0;
  for (int t = 0; t < Tn; ++t) {
    float a     = arow[t];
    float integ = integrate + a;          // same order as reference
    bool  fire  = integ > kThresh;
    float cur   = fire ? (1.0f - integrate) : a;
    w1r[t] = cur;
    w2r[t] = fire ? (a - cur) : 0.0f;     // remainder -> next segment
    sgr[t] = fc;
    if (fire) { fc += 1; integrate = integ - 1.0f; }
    else      { integrate = integ; }
  }
  fcnt[b] = fc;
}

// ---------------------------------------------------------------------------
// Phase 2: segmented weighted accumulation of hidden into output frames.
// Grid: (B, NTCH) blocks, 128 threads, each thread owns 4 consecutive floats
// of the H=512 row (float4, fully coalesced 2 KB per block per timestep).
// Segments are monotone non-decreasing in t, so accumulate in registers and
// flush on segment change; atomicAdd handles chunk-boundary segments.
// ---------------------------------------------------------------------------
__global__ __launch_bounds__(128) void cif_accum_kernel(
    const float* __restrict__ hidden,
    const float* __restrict__ w1,
    const float* __restrict__ w2,
    const int* __restrict__ seg,
    const int* __restrict__ fcnt,
    float* __restrict__ out) {
  const int b  = blockIdx.x;
  const int tc = blockIdx.y;
  const int t0 = tc * TCHUNK;
  const int t1 = t0 + TCHUNK;
  const int col = threadIdx.x * 4;

  const int fb    = fcnt[b];
  const int limit = fb < Ln ? fb : Ln;   // segments >= limit are never emitted

  const float* hbase = hidden + (size_t)b * Tn * Hn + col;
  float*       obase = out    + (size_t)b * Ln * Hn + col;
  const int    rb    = b * Tn;

  float4 acc = make_float4(0.f, 0.f, 0.f, 0.f);
  int curseg = seg[rb + t0];

  for (int t = t0; t < t1; ++t) {
    const int s = seg[rb + t];
    if (s != curseg) {
      if (curseg < limit) {
        float* o = obase + (size_t)curseg * Hn;
        atomicAdd(o + 0, acc.x);
        atomicAdd(o + 1, acc.y);
        atomicAdd(o + 2, acc.z);
        atomicAdd(o + 3, acc.w);
      }
      acc = make_float4(0.f, 0.f, 0.f, 0.f);
      curseg = s;
    }
    const float4 h = *reinterpret_cast<const float4*>(hbase + (size_t)t * Hn);
    const float a1 = w1[rb + t];
    acc.x += a1 * h.x;
    acc.y += a1 * h.y;
    acc.z += a1 * h.z;
    acc.w += a1 * h.w;
    const float a2 = w2[rb + t];
    if (a2 != 0.0f) {  // fire with nonzero remainder: close segment s, open s+1
      if (s < limit) {
        float* o = obase + (size_t)s * Hn;
        atomicAdd(o + 0, acc.x);
        atomicAdd(o + 1, acc.y);
        atomicAdd(o + 2, acc.z);
        atomicAdd(o + 3, acc.w);
      }
      acc.x = a2 * h.x;
      acc.y = a2 * h.y;
      acc.z = a2 * h.z;
      acc.w = a2 * h.w;
      curseg = s + 1;
    }
  }
  if (curseg < limit) {
    float* o = obase + (size_t)curseg * Hn;
    atomicAdd(o + 0, acc.x);
    atomicAdd(o + 1, acc.y);
    atomicAdd(o + 2, acc.z);
    atomicAdd(o + 3, acc.w);
  }
}

extern "C" void kernel_launch(void* const* d_in, const int* in_sizes, int n_in,
                              void* d_out, int out_size, void* d_ws, size_t ws_size,
                              hipStream_t stream) {
  const float* hidden = (const float*)d_in[0];
  const float* alphas = (const float*)d_in[1];
  float* out = (float*)d_out;

  // ws layout: w1[B*T] f32 | w2[B*T] f32 | seg[B*T] i32 | fcnt[B] i32  (~768 KB)
  float* w1   = (float*)d_ws;
  float* w2   = w1 + (size_t)Bn * Tn;
  int*   segp = (int*)(w2 + (size_t)Bn * Tn);
  int*   fcnt = segp + (size_t)Bn * Tn;

  // Output must be zero for non-fired slots (harness poisons with 0xAA).
  hipMemsetAsync(d_out, 0, (size_t)out_size * sizeof(float), stream);

  cif_scan_kernel<<<1, 64, 0, stream>>>(alphas, w1, w2, segp, fcnt);

  dim3 grid(Bn, NTCH);
  cif_accum_kernel<<<grid, 128, 0, stream>>>(hidden, w1, w2, segp, fcnt, out);
}

// Round 2
// 118.818 us; speedup vs baseline: 1.8558x; 1.8558x over previous
//
#include <hip/hip_runtime.h>

static constexpr int   Bn      = 32;
static constexpr int   Tn      = 2000;
static constexpr int   Hn      = 512;
static constexpr int   Ln      = 256;     // max_label_len
static constexpr float kThresh = 0.95f;
static constexpr int   TCHUNK  = 40;
static constexpr int   NTCH    = Tn / TCHUNK;   // 50

// ---------------------------------------------------------------------------
// Phase 1: per-batch-row sequential integrate-and-fire scan. Bit-exact f32
// replay of the reference recurrence (same op order -> identical fire bits).
// Loads are software-pipelined: 80-step chunks staged through registers as
// 20x float4, double-buffered, so the serial chain never waits on VMEM.
// Outputs: w12[t] = (w1, w2) weights, seg[t] = pending fire index, fcnt[b].
// ---------------------------------------------------------------------------
__global__ __launch_bounds__(64) void cif_scan_kernel(
    const float* __restrict__ alphas,
    float2* __restrict__ w12,
    int* __restrict__ seg,
    int* __restrict__ fcnt) {
  const int b = threadIdx.x;
  if (b >= Bn) return;
  const float4* __restrict__ arow =
      reinterpret_cast<const float4*>(alphas + (size_t)b * Tn);
  float2* __restrict__ w12r = w12 + (size_t)b * Tn;
  int*    __restrict__ sgr  = seg + (size_t)b * Tn;

  constexpr int CH  = 80;        // timesteps per chunk
  constexpr int CV  = CH / 4;    // 20 float4 per chunk
  constexpr int NCH = Tn / CH;   // 25

  float integrate = 0.0f;
  int   fc        = 0;

  float4 cur[CV], nxt[CV];
#pragma unroll
  for (int i = 0; i < CV; ++i) cur[i] = arow[i];

  for (int c = 0; c < NCH; ++c) {
    const bool more = (c + 1 < NCH);
    if (more) {
#pragma unroll
      for (int i = 0; i < CV; ++i) nxt[i] = arow[(size_t)(c + 1) * CV + i];
    }
    const int tbase = c * CH;
#pragma unroll
    for (int i = 0; i < CV; ++i) {
      const float a4[4] = {cur[i].x, cur[i].y, cur[i].z, cur[i].w};
#pragma unroll
      for (int j = 0; j < 4; ++j) {
        const int t     = tbase + i * 4 + j;
        const float a   = a4[j];
        const float integ = integrate + a;      // reference op order
        const bool  fire  = integ > kThresh;
        const float comp  = 1.0f - integrate;   // dist_completion
        const float cw    = fire ? comp : a;
        const float rem   = fire ? (a - cw) : 0.0f;
        w12r[t] = make_float2(cw, rem);
        sgr[t]  = fc;
        integrate = fire ? (integ - 1.0f) : integ;
        fc += fire ? 1 : 0;
      }
    }
    if (more) {
#pragma unroll
      for (int i = 0; i < CV; ++i) cur[i] = nxt[i];
    }
  }
  fcnt[b] = fc;
}

// ---------------------------------------------------------------------------
// Phase 2: segmented weighted accumulation of hidden into output frames.
// Grid (B, NTCH) x 128 threads; each thread owns 4 consecutive floats of the
// H=512 row (coalesced float4, 2 KB/timestep/block). Segments are monotone in
// t: accumulate in registers, flush on segment close. Only the chunk's FIRST
// segment (may receive the previous chunk's tail) and the final OPEN segment
// (spills into the next chunk) are shared -> atomicAdd; interior segments are
// exclusive to this block -> plain float4 store (out is pre-zeroed).
// ---------------------------------------------------------------------------
__global__ __launch_bounds__(128) void cif_accum_kernel(
    const float* __restrict__ hidden,
    const float2* __restrict__ w12,
    const int* __restrict__ seg,
    const int* __restrict__ fcnt,
    float* __restrict__ out) {
  const int b   = blockIdx.x;
  const int tc  = blockIdx.y;
  const int t0  = tc * TCHUNK;
  const int t1  = t0 + TCHUNK;
  const int col = threadIdx.x * 4;

  const int fb    = fcnt[b];
  const int limit = fb < Ln ? fb : Ln;   // segments >= limit are never emitted

  const float* hbase = hidden + (size_t)b * Tn * Hn + col;
  float*       obase = out    + (size_t)b * Ln * Hn + col;
  const int    rb    = b * Tn;

  const int seg0 = seg[rb + t0];

  float4 acc    = make_float4(0.f, 0.f, 0.f, 0.f);
  int    curseg = seg0;

  auto flush = [&](int sg, float4 v, bool shared) {
    if (sg < limit) {
      float* o = obase + (size_t)sg * Hn;
      if (shared) {
        atomicAdd(o + 0, v.x);
        atomicAdd(o + 1, v.y);
        atomicAdd(o + 2, v.z);
        atomicAdd(o + 3, v.w);
      } else {
        *reinterpret_cast<float4*>(o) = v;   // exclusive: plain store
      }
    }
  };

  for (int t = t0; t < t1; ++t) {
    const int s = seg[rb + t];
    if (s != curseg) {               // fire with exactly-zero remainder
      flush(curseg, acc, curseg == seg0);
      acc    = make_float4(0.f, 0.f, 0.f, 0.f);
      curseg = s;
    }
    const float4 h = *reinterpret_cast<const float4*>(hbase + (size_t)t * Hn);
    const float2 w = w12[rb + t];
    acc.x += w.x * h.x;
    acc.y += w.x * h.y;
    acc.z += w.x * h.z;
    acc.w += w.x * h.w;
    if (w.y != 0.0f) {               // fire: close segment s, open s+1
      flush(s, acc, s == seg0);
      acc.x  = w.y * h.x;
      acc.y  = w.y * h.y;
      acc.z  = w.y * h.z;
      acc.w  = w.y * h.w;
      curseg = s + 1;
    }
  }
  flush(curseg, acc, true);          // open segment: may continue next chunk
}

extern "C" void kernel_launch(void* const* d_in, const int* in_sizes, int n_in,
                              void* d_out, int out_size, void* d_ws, size_t ws_size,
                              hipStream_t stream) {
  const float* hidden = (const float*)d_in[0];
  const float* alphas = (const float*)d_in[1];
  float* out = (float*)d_out;

  // ws layout: w12[B*T] float2 (512 KB) | seg[B*T] i32 (256 KB) | fcnt[B] i32
  float2* w12  = (float2*)d_ws;
  int*    segp = (int*)(w12 + (size_t)Bn * Tn);
  int*    fcnt = segp + (size_t)Bn * Tn;

  // Output must be zero (harness poisons with 0xAA; non-fired slots stay 0).
  hipMemsetAsync(d_out, 0, (size_t)out_size * sizeof(float), stream);

  cif_scan_kernel<<<1, 64, 0, stream>>>(alphas, w12, segp, fcnt);

  dim3 grid(Bn, NTCH);
  cif_accum_kernel<<<grid, 128, 0, stream>>>(hidden, w12, segp, fcnt, out);
}